// Round 2
// baseline (1256.767 us; speedup 1.0000x reference)
//
#include <hip/hip_runtime.h>

// GridSamplePScan on MI355X — R2: XCD-chunked block swizzle + float4 copy region.
// 5 log-scan passes (step=1,2,4,8,16). Each pass: per output pixel compute the
// wrapped sample grid from the current flow, bilinear-sample previous flow
// (border pad) and previous image (zeros pad), add, write.
// Images ping-pong between d_in[1] and d_out (harness restores d_in each call);
// flows ping-pong inside d_ws (2 x 16 MiB).

constexpr int Bn = 4, Ln = 32, Cn = 16, Hn = 128, Wn = 128;
constexpr int HWp = Hn * Wn;                    // 16384
constexpr int FLOW_ELEMS = Bn * Ln * 2 * HWp;   // 4,194,304
constexpr int TOTAL_PIX = Bn * Ln * HWp;        // 2,097,152
constexpr int NBLK = TOTAL_PIX / 256;           // 8192
constexpr int NXCD = 8;
constexpr int CHUNK = NBLK / NXCD;              // 1024 blocks = 16 frames per XCD

template<bool NEED_FLOW>
__global__ __launch_bounds__(256)
void pscan_pass(const float* __restrict__ flowIn,
                const float* __restrict__ imgIn,
                float* __restrict__ flowOut,
                float* __restrict__ imgOut,
                int step)
{
    // XCD-chunked swizzle: consecutive hardware blocks round-robin XCDs, so
    // give XCD x the contiguous chunk [x*CHUNK, (x+1)*CHUNK). 8192 % 8 == 0.
    const int n = (blockIdx.x & (NXCD - 1)) * CHUNK + (blockIdx.x >> 3);
    const int b   = n >> 11;          // 2048 blocks per batch
    const int l   = (n >> 6) & 31;    // 64 blocks per frame
    const int blk = n & 63;           // 2 rows per block
    const int h0  = blk << 1;

    const int tid = threadIdx.x;
    const int fframe = ((b * Ln + l) * 2) * HWp;
    const int iframe = ((b * Ln + l) * Cn) * HWp;
    const int rowbase = h0 * Wn;      // 256 consecutive pixels (2 rows)

    if (l < step) {   // prefix: plain copy, vectorized float4 (wave-uniform branch)
        if (NEED_FLOW) {
            if (tid < 128) {          // 2 ch * 64 float4
                const int ch = tid >> 6, f4 = (tid & 63) << 2;
                const int off = fframe + ch * HWp + rowbase + f4;
                *(float4*)&flowOut[off] = *(const float4*)&flowIn[off];
            }
        }
        #pragma unroll
        for (int k = 0; k < 4; ++k) { // 16 ch * 64 float4 = 1024 float4
            const int idx = tid + k * 256;
            const int c = idx >> 6, f4 = (idx & 63) << 2;
            const int off = iframe + c * HWp + rowbase + f4;
            *(float4*)&imgOut[off] = *(const float4*)&imgIn[off];
        }
        return;
    }

    const int w = tid & (Wn - 1);
    const int h = h0 + (tid >> 7);
    const int pix = h * Wn + w;
    const int fbase = fframe + pix;
    const int ibase = iframe + pix;

    // current flow -> sample grid
    const float fcx = flowIn[fbase];
    const float fcy = flowIn[fbase + HWp];
    float gx = (w + 0.5f) * (2.0f / Wn) - 1.0f + fcx;
    float gy = (h + 0.5f) * (2.0f / Hn) - 1.0f + fcy;

    // wrap x: remainder(gx+1, 2) - 1  (numpy mod semantics, divisor > 0)
    float t = gx + 1.0f;
    float r = fmodf(t, 2.0f);
    if (r < 0.0f) r += 2.0f;
    const float gxw = r - 1.0f;

    // unnormalize (align_corners=False)
    const float x = (gxw + 1.0f) * (Wn * 0.5f) - 0.5f;
    const float y = (gy  + 1.0f) * (Hn * 0.5f) - 0.5f;
    const float x0f = floorf(x), y0f = floorf(y);
    const float wx = x - x0f,    wy = y - y0f;
    const int x0 = (int)x0f, y0 = (int)y0f;
    const int x1 = x0 + 1,   y1 = y0 + 1;

    const int xc0 = min(max(x0, 0), Wn - 1), xc1 = min(max(x1, 0), Wn - 1);
    const int yc0 = min(max(y0, 0), Hn - 1), yc1 = min(max(y1, 0), Hn - 1);
    const int o00 = yc0 * Wn + xc0, o01 = yc0 * Wn + xc1;
    const int o10 = yc1 * Wn + xc0, o11 = yc1 * Wn + xc1;

    const float w00 = (1.0f - wx) * (1.0f - wy);
    const float w01 = wx * (1.0f - wy);
    const float w10 = (1.0f - wx) * wy;
    const float w11 = wx * wy;

    // ---- flows: border padding (clamped, unmasked) ----
    if (NEED_FLOW) {
        const int fprev = ((b * Ln + (l - step)) * 2) * HWp;
        const float* __restrict__ fp0 = flowIn + fprev;
        const float* __restrict__ fp1 = flowIn + fprev + HWp;
        const float sx = w00 * fp0[o00] + w01 * fp0[o01] + w10 * fp0[o10] + w11 * fp0[o11];
        const float sy = w00 * fp1[o00] + w01 * fp1[o01] + w10 * fp1[o10] + w11 * fp1[o11];
        flowOut[fbase]       = fcx + sx;
        flowOut[fbase + HWp] = fcy + sy;
    }

    // ---- images: zeros padding (mask folded into weights) ----
    const bool vx0 = (x0 >= 0) & (x0 < Wn);
    const bool vx1 = (x1 >= 0) & (x1 < Wn);
    const bool vy0 = (y0 >= 0) & (y0 < Hn);
    const bool vy1 = (y1 >= 0) & (y1 < Hn);
    const float m00 = (vy0 & vx0) ? w00 : 0.0f;
    const float m01 = (vy0 & vx1) ? w01 : 0.0f;
    const float m10 = (vy1 & vx0) ? w10 : 0.0f;
    const float m11 = (vy1 & vx1) ? w11 : 0.0f;

    const int iprev = ((b * Ln + (l - step)) * Cn) * HWp;
    const float* __restrict__ ip = imgIn + iprev;
    #pragma unroll
    for (int c = 0; c < Cn; ++c) {
        const int co = c * HWp;
        const float icv = imgIn[ibase + co];
        const float v = m00 * ip[co + o00] + m01 * ip[co + o01]
                      + m10 * ip[co + o10] + m11 * ip[co + o11];
        imgOut[ibase + co] = icv + v;
    }
}

extern "C" void kernel_launch(void* const* d_in, const int* in_sizes, int n_in,
                              void* d_out, int out_size, void* d_ws, size_t ws_size,
                              hipStream_t stream) {
    const float* f_in = (const float*)d_in[0];   // flows  [4,32,2,128,128]
    float* i_io       = (float*)d_in[1];         // images [4,32,16,128,128] (harness restores each call)
    float* i_out      = (float*)d_out;

    float* fA = (float*)d_ws;            // 16 MiB
    float* fB = fA + FLOW_ELEMS;         // 16 MiB

    // pass 1, step=1 : flows IN->fA, images IN->OUT
    pscan_pass<true ><<<NBLK, 256, 0, stream>>>(f_in, i_io, fA, i_out, 1);
    // pass 2, step=2 : flows fA->fB, images OUT->IN
    pscan_pass<true ><<<NBLK, 256, 0, stream>>>(fA, i_out, fB, i_io, 2);
    // pass 3, step=4 : flows fB->fA, images IN->OUT
    pscan_pass<true ><<<NBLK, 256, 0, stream>>>(fB, i_io, fA, i_out, 4);
    // pass 4, step=8 : flows fA->fB, images OUT->IN
    pscan_pass<true ><<<NBLK, 256, 0, stream>>>(fA, i_out, fB, i_io, 8);
    // pass 5, step=16: flows read fB (no write), images IN->OUT
    pscan_pass<false><<<NBLK, 256, 0, stream>>>(fB, i_io, nullptr, i_out, 16);
}

// Round 3
// 725.770 us; speedup vs baseline: 1.7316x; 1.7316x over previous
//
#include <hip/hip_runtime.h>

// GridSamplePScan on MI355X — R3: NHWC layout + (pixel,quad) lane mapping so
// each bilinear tap fetches a whole 64B pixel-line coalesced.
// 5 log-scan passes (step=1,2,4,8,16) + optional layout-convert pre-pass.
// Flows ping-pong in d_ws (HWC); images ping-pong NHWC between d_in[1] and
// (if ws_size allows) a 128 MiB ws buffer, final pass writes NCHW to d_out.

constexpr int Bn = 4, Ln = 32, Cn = 16, Hn = 128, Wn = 128;
constexpr int HWp = Hn * Wn;                     // 16384
constexpr int FLOW_ELEMS = Bn * Ln * 2 * HWp;    // 4,194,304 floats
constexpr int IMG_ELEMS  = Bn * Ln * Cn * HWp;   // 33,554,432 floats
constexpr int TOTAL_PIX  = Bn * Ln * HWp;        // 2,097,152
constexpr int PX_PER_BLK = 64;                   // 256 thr = 64 px * 4 quads
constexpr int NBLK = TOTAL_PIX / PX_PER_BLK;     // 32768
constexpr int NXCD = 8, CHUNK = NBLK / NXCD;     // 4096

// IN_NCHW:  layout of imgIn (cur + gather source). OUT_NCHW: layout of imgOut.
// FLOW_NCHW: layout of flowIn.  flowOut is always HWC. NEED_FLOW: write flows.
template<bool IN_NCHW, bool OUT_NCHW, bool FLOW_NCHW, bool NEED_FLOW>
__global__ __launch_bounds__(256)
void pscan_pass(const float* __restrict__ flowIn,
                const float* __restrict__ imgIn,
                float* __restrict__ flowOut,
                float* __restrict__ imgOut,
                int step)
{
    const int n    = (blockIdx.x & (NXCD - 1)) * CHUNK + (blockIdx.x >> 3);
    const int t    = threadIdx.x;
    const int quad = t & 3;          // which 4-channel group
    const int pxl  = t >> 2;         // 0..63 pixel within block
    const int P    = n * PX_PER_BLK + pxl;       // global pixel id
    const int b    = P >> 19;
    const int l    = (P >> 14) & 31;
    const int pix  = P & (HWp - 1);
    const int h    = pix >> 7, w = pix & 127;

    const size_t fframe = (size_t)(b * Ln + l) * (2 * HWp);
    const size_t iframe = (size_t)(b * Ln + l) * (Cn * HWp);

    // current flow at my pixel
    float fcx, fcy;
    if (FLOW_NCHW) {
        fcx = flowIn[fframe + pix];
        fcy = flowIn[fframe + HWp + pix];
    } else {
        const float2 fc = *(const float2*)&flowIn[fframe + 2 * (size_t)pix];
        fcx = fc.x; fcy = fc.y;
    }

    // current image, my quad (4 channels)
    float4 cur;
    if (IN_NCHW) {
        const int c0 = quad * 4;
        cur.x = imgIn[iframe + (size_t)(c0 + 0) * HWp + pix];
        cur.y = imgIn[iframe + (size_t)(c0 + 1) * HWp + pix];
        cur.z = imgIn[iframe + (size_t)(c0 + 2) * HWp + pix];
        cur.w = imgIn[iframe + (size_t)(c0 + 3) * HWp + pix];
    } else {
        cur = *(const float4*)&imgIn[iframe + (size_t)pix * Cn + quad * 4];
    }

    float4 outv = cur;
    float2 outf = make_float2(fcx, fcy);

    if (l >= step) {
        // grid (identical arithmetic to R1/R2)
        float gx = (w + 0.5f) * (2.0f / Wn) - 1.0f + fcx;
        float gy = (h + 0.5f) * (2.0f / Hn) - 1.0f + fcy;
        float tt = gx + 1.0f;
        float r  = fmodf(tt, 2.0f);
        if (r < 0.0f) r += 2.0f;
        const float gxw = r - 1.0f;

        const float x = (gxw + 1.0f) * (Wn * 0.5f) - 0.5f;
        const float y = (gy  + 1.0f) * (Hn * 0.5f) - 0.5f;
        const float x0f = floorf(x), y0f = floorf(y);
        const float wx = x - x0f,    wy = y - y0f;
        const int x0 = (int)x0f, y0 = (int)y0f;
        const int x1 = x0 + 1,   y1 = y0 + 1;

        const int xc0 = min(max(x0, 0), Wn - 1), xc1 = min(max(x1, 0), Wn - 1);
        const int yc0 = min(max(y0, 0), Hn - 1), yc1 = min(max(y1, 0), Hn - 1);
        const int o00 = yc0 * Wn + xc0, o01 = yc0 * Wn + xc1;
        const int o10 = yc1 * Wn + xc0, o11 = yc1 * Wn + xc1;

        const float w00 = (1.0f - wx) * (1.0f - wy);
        const float w01 = wx * (1.0f - wy);
        const float w10 = (1.0f - wx) * wy;
        const float w11 = wx * wy;

        // flows: border padding (clamped, unmasked)
        if (NEED_FLOW) {
            const size_t fprev = (size_t)(b * Ln + (l - step)) * (2 * HWp);
            float sx, sy;
            if (FLOW_NCHW) {
                const float* __restrict__ fp0 = flowIn + fprev;
                const float* __restrict__ fp1 = flowIn + fprev + HWp;
                sx = w00*fp0[o00] + w01*fp0[o01] + w10*fp0[o10] + w11*fp0[o11];
                sy = w00*fp1[o00] + w01*fp1[o01] + w10*fp1[o10] + w11*fp1[o11];
            } else {
                const float* __restrict__ fp = flowIn + fprev;
                const float2 t00 = *(const float2*)&fp[2*o00];
                const float2 t01 = *(const float2*)&fp[2*o01];
                const float2 t10 = *(const float2*)&fp[2*o10];
                const float2 t11 = *(const float2*)&fp[2*o11];
                sx = w00*t00.x + w01*t01.x + w10*t10.x + w11*t11.x;
                sy = w00*t00.y + w01*t01.y + w10*t10.y + w11*t11.y;
            }
            outf = make_float2(fcx + sx, fcy + sy);
        }

        // images: zeros padding (mask folded into weights)
        const bool vx0 = (x0 >= 0) & (x0 < Wn);
        const bool vx1 = (x1 >= 0) & (x1 < Wn);
        const bool vy0 = (y0 >= 0) & (y0 < Hn);
        const bool vy1 = (y1 >= 0) & (y1 < Hn);
        const float m00 = (vy0 & vx0) ? w00 : 0.0f;
        const float m01 = (vy0 & vx1) ? w01 : 0.0f;
        const float m10 = (vy1 & vx0) ? w10 : 0.0f;
        const float m11 = (vy1 & vx1) ? w11 : 0.0f;

        const size_t iprev = (size_t)(b * Ln + (l - step)) * (Cn * HWp);
        const float* __restrict__ ip = imgIn + iprev;
        if (IN_NCHW) {
            const int c0 = quad * 4;
            float v[4];
            #pragma unroll
            for (int j = 0; j < 4; ++j) {
                const size_t co = (size_t)(c0 + j) * HWp;
                v[j] = m00*ip[co+o00] + m01*ip[co+o01] + m10*ip[co+o10] + m11*ip[co+o11];
            }
            outv = make_float4(cur.x + v[0], cur.y + v[1], cur.z + v[2], cur.w + v[3]);
        } else {
            const float4 t00 = *(const float4*)&ip[(size_t)o00 * Cn + quad*4];
            const float4 t01 = *(const float4*)&ip[(size_t)o01 * Cn + quad*4];
            const float4 t10 = *(const float4*)&ip[(size_t)o10 * Cn + quad*4];
            const float4 t11 = *(const float4*)&ip[(size_t)o11 * Cn + quad*4];
            outv.x = cur.x + (m00*t00.x + m01*t01.x + m10*t10.x + m11*t11.x);
            outv.y = cur.y + (m00*t00.y + m01*t01.y + m10*t10.y + m11*t11.y);
            outv.z = cur.z + (m00*t00.z + m01*t01.z + m10*t10.z + m11*t11.z);
            outv.w = cur.w + (m00*t00.w + m01*t01.w + m10*t10.w + m11*t11.w);
        }
    }

    // stores
    if (NEED_FLOW) {
        if (quad == 0)
            *(float2*)&flowOut[fframe + 2 * (size_t)pix] = outf;  // HWC
    }
    if (OUT_NCHW) {
        const int c0 = quad * 4;
        imgOut[iframe + (size_t)(c0 + 0) * HWp + pix] = outv.x;
        imgOut[iframe + (size_t)(c0 + 1) * HWp + pix] = outv.y;
        imgOut[iframe + (size_t)(c0 + 2) * HWp + pix] = outv.z;
        imgOut[iframe + (size_t)(c0 + 3) * HWp + pix] = outv.w;
    } else {
        *(float4*)&imgOut[iframe + (size_t)pix * Cn + quad * 4] = outv;
    }
}

extern "C" void kernel_launch(void* const* d_in, const int* in_sizes, int n_in,
                              void* d_out, int out_size, void* d_ws, size_t ws_size,
                              hipStream_t stream) {
    const float* f_in = (const float*)d_in[0];   // flows  [4,32,2,128,128] NCHW
    float* i_io       = (float*)d_in[1];         // images [4,32,16,128,128] (restored each call)
    float* i_out      = (float*)d_out;

    float* fA = (float*)d_ws;                    // 16 MiB HWC flows
    float* fB = fA + FLOW_ELEMS;                 // 16 MiB
    float* iW = fB + FLOW_ELEMS;                 // 128 MiB NHWC images (if it fits)

    const size_t need = (size_t)(2 * FLOW_ELEMS + IMG_ELEMS) * sizeof(float);

    #define CONV pscan_pass<true , false, true , true >   // NCHW in -> NHWC out
    #define MID  pscan_pass<false, false, false, true >   // NHWC -> NHWC
    #define LAST pscan_pass<false, true , false, false>   // NHWC -> NCHW, no flow

    if (ws_size >= need) {
        // pre-pass: pure layout conversion (step=32 => copy path everywhere)
        CONV<<<NBLK, 256, 0, stream>>>(f_in, i_io, fA, iW,   32);
        MID <<<NBLK, 256, 0, stream>>>(fA,   iW,   fB, i_io,  1);
        MID <<<NBLK, 256, 0, stream>>>(fB,   i_io, fA, iW,    2);
        MID <<<NBLK, 256, 0, stream>>>(fA,   iW,   fB, i_io,  4);
        MID <<<NBLK, 256, 0, stream>>>(fB,   i_io, fA, iW,    8);
        LAST<<<NBLK, 256, 0, stream>>>(fA,   iW,   nullptr, i_out, 16);
    } else {
        // fallback: no NHWC ws buffer; pass 1 gathers in NCHW (slower, correct)
        CONV<<<NBLK, 256, 0, stream>>>(f_in, i_io, fA, i_out,  1);
        MID <<<NBLK, 256, 0, stream>>>(fA,   i_out, fB, i_io,  2);
        MID <<<NBLK, 256, 0, stream>>>(fB,   i_io,  fA, i_out, 4);
        MID <<<NBLK, 256, 0, stream>>>(fA,   i_out, fB, i_io,  8);
        LAST<<<NBLK, 256, 0, stream>>>(fB,   i_io,  nullptr, i_out, 16);
    }
    #undef CONV
    #undef MID
    #undef LAST
}